// Round 1
// baseline (9074.554 us; speedup 1.0000x reference)
//
#include <hip/hip_runtime.h>
#include <hip/hip_bf16.h>

#define LQ 1024
#define NHEAD 16
#define DNOPE 128
#define DROPE 64
#define DV 128
#define DKVR 512
#define DQ 192      // NOPE+ROPE
#define DKC 576     // KVR+ROPE
#define QSTR 580    // padded float stride for 576-wide LDS rows

// ---------------- generic fp32 GEMM: C[m,n] = sum_k A[m,k] * B[n,k] ----------------
// grid: (N/64, M/64), block 256. K, lda, ldb, ldc multiples of 4 (K mult of 32).
__global__ __launch_bounds__(256) void gemm_nt(
    const float* __restrict__ A, const float* __restrict__ B, float* __restrict__ C,
    int K, int lda, int ldb, int ldc) {
  __shared__ float As[32][64];  // [k][m]
  __shared__ float Bs[32][64];  // [k][n]
  const int tid = threadIdx.x;
  const int tx = tid & 15, ty = tid >> 4;
  const int m0 = blockIdx.y * 64, n0 = blockIdx.x * 64;
  const int lm = tid >> 2, lk = (tid & 3) * 8;
  float acc[4][4] = {};
  for (int k0 = 0; k0 < K; k0 += 32) {
    __syncthreads();
    {
      const float* ap = A + (size_t)(m0 + lm) * lda + k0 + lk;
      float4 a0 = *(const float4*)ap;
      float4 a1 = *(const float4*)(ap + 4);
      As[lk + 0][lm] = a0.x; As[lk + 1][lm] = a0.y; As[lk + 2][lm] = a0.z; As[lk + 3][lm] = a0.w;
      As[lk + 4][lm] = a1.x; As[lk + 5][lm] = a1.y; As[lk + 6][lm] = a1.z; As[lk + 7][lm] = a1.w;
      const float* bp = B + (size_t)(n0 + lm) * ldb + k0 + lk;
      float4 b0 = *(const float4*)bp;
      float4 b1 = *(const float4*)(bp + 4);
      Bs[lk + 0][lm] = b0.x; Bs[lk + 1][lm] = b0.y; Bs[lk + 2][lm] = b0.z; Bs[lk + 3][lm] = b0.w;
      Bs[lk + 4][lm] = b1.x; Bs[lk + 5][lm] = b1.y; Bs[lk + 6][lm] = b1.z; Bs[lk + 7][lm] = b1.w;
    }
    __syncthreads();
#pragma unroll 8
    for (int kk = 0; kk < 32; ++kk) {
      float4 av = *(const float4*)&As[kk][ty * 4];
      float4 bv = *(const float4*)&Bs[kk][tx * 4];
      acc[0][0] += av.x * bv.x; acc[0][1] += av.x * bv.y; acc[0][2] += av.x * bv.z; acc[0][3] += av.x * bv.w;
      acc[1][0] += av.y * bv.x; acc[1][1] += av.y * bv.y; acc[1][2] += av.y * bv.z; acc[1][3] += av.y * bv.w;
      acc[2][0] += av.z * bv.x; acc[2][1] += av.z * bv.y; acc[2][2] += av.z * bv.z; acc[2][3] += av.z * bv.w;
      acc[3][0] += av.w * bv.x; acc[3][1] += av.w * bv.y; acc[3][2] += av.w * bv.z; acc[3][3] += av.w * bv.w;
    }
  }
#pragma unroll
  for (int i = 0; i < 4; ++i) {
    float4 o = make_float4(acc[i][0], acc[i][1], acc[i][2], acc[i][3]);
    *(float4*)(C + (size_t)(m0 + ty * 4 + i) * ldc + n0 + tx * 4) = o;
  }
}

// ---------------- RMSNorm in-place over rows of length 1024 (one wave per row) ----------------
__global__ __launch_bounds__(64) void rmsnorm1024(float* __restrict__ t, const float* __restrict__ w) {
  const int row = blockIdx.x;
  const int lane = threadIdx.x;
  float4* p = (float4*)(t + (size_t)row * 1024);
  const float4* w4 = (const float4*)w;
  float4 v[4];
  float ss = 0.f;
#pragma unroll
  for (int i = 0; i < 4; ++i) {
    v[i] = p[lane * 4 + i];
    ss += v[i].x * v[i].x + v[i].y * v[i].y + v[i].z * v[i].z + v[i].w * v[i].w;
  }
#pragma unroll
  for (int off = 32; off >= 1; off >>= 1) ss += __shfl_xor(ss, off, 64);
  const float rms = rsqrtf(ss * (1.0f / 1024.0f) + 1e-6f);
#pragma unroll
  for (int i = 0; i < 4; ++i) {
    float4 wv = w4[lane * 4 + i];
    float4 o = v[i];
    o.x *= rms * wv.x; o.y *= rms * wv.y; o.z *= rms * wv.z; o.w *= rms * wv.w;
    p[lane * 4 + i] = o;
  }
}

// ---------------- kv (4096,576) -> kvc: rmsnorm first 512, rope last 64 ----------------
__global__ __launch_bounds__(64) void prep_kv(
    const float* __restrict__ kv, const float* __restrict__ freq,
    const float* __restrict__ w, float* __restrict__ kvc) {
  const int row = blockIdx.x;
  const int l = row & (LQ - 1);
  const int lane = threadIdx.x;
  const float* src = kv + (size_t)row * DKC;
  float* dst = kvc + (size_t)row * DKC;
  const float4* s4 = (const float4*)src;
  const float4* w4 = (const float4*)w;
  float4 v[2];
  float ss = 0.f;
#pragma unroll
  for (int i = 0; i < 2; ++i) {
    v[i] = s4[lane * 2 + i];
    ss += v[i].x * v[i].x + v[i].y * v[i].y + v[i].z * v[i].z + v[i].w * v[i].w;
  }
#pragma unroll
  for (int off = 32; off >= 1; off >>= 1) ss += __shfl_xor(ss, off, 64);
  const float rms = rsqrtf(ss * (1.0f / 512.0f) + 1e-6f);
  float4* d4 = (float4*)dst;
#pragma unroll
  for (int i = 0; i < 2; ++i) {
    float4 wv = w4[lane * 2 + i];
    float4 o = v[i];
    o.x *= rms * wv.x; o.y *= rms * wv.y; o.z *= rms * wv.z; o.w *= rms * wv.w;
    d4[lane * 2 + i] = o;
  }
  if (lane < 32) {
    const int j = lane;
    const float re = src[DKVR + 2 * j], im = src[DKVR + 2 * j + 1];
    const float c = freq[(l * 32 + j) * 2], s = freq[(l * 32 + j) * 2 + 1];
    dst[DKVR + 2 * j] = re * c - im * s;
    dst[DKVR + 2 * j + 1] = re * s + im * c;
  }
}

// ---------------- rope on q's [128:192] per head, in place ----------------
__global__ __launch_bounds__(64) void rope_q(float* __restrict__ q, const float* __restrict__ freq) {
  const int row = blockIdx.x;             // b*1024 + l
  const int l = row & (LQ - 1);
  float* base = q + (size_t)row * (NHEAD * DQ);
#pragma unroll
  for (int i = 0; i < 8; ++i) {
    const int pi = threadIdx.x * 8 + i;   // 0..511 pair index
    const int h = pi >> 5, j = pi & 31;
    float* p = base + h * DQ + DNOPE + 2 * j;
    const float re = p[0], im = p[1];
    const float c = freq[(l * 32 + j) * 2], s = freq[(l * 32 + j) * 2 + 1];
    p[0] = re * c - im * s;
    p[1] = re * s + im * c;
  }
}

// ---------------- fused MLA attention ----------------
// grid (L/32, H, B), block 256. Per block: 32 query rows of one (b,h).
// Computes q_abs in-kernel, flash softmax over kvc, then v-epilogue into vout.
__global__ __launch_bounds__(256) void mla_attn(
    const float* __restrict__ q, const float* __restrict__ kvc,
    const float* __restrict__ Wup, float* __restrict__ vout) {
  __shared__ float Qs[32 * QSTR];   // q_cat tile: [0:512]=q_abs, [512:576]=q_rope
  __shared__ float Ks[32 * QSTR];   // K/V tile (also temp q_nope, also O staging)
  __shared__ float Ps[32 * 32];
  const int tid = threadIdx.x;
  const int r = tid >> 3;           // query row within tile (0..31)
  const int g = tid & 7;            // column group (0..7)
  const int b = blockIdx.z, h = blockIdx.y;
  const int l0 = blockIdx.x * 32;

  // ---- stage q_nope into Ks[r][0:128], q_rope into Qs[r][512:576]
  {
    const float* qrow = q + (size_t)(b * LQ + l0 + r) * (NHEAD * DQ) + h * DQ;
    const float4* s4 = (const float4*)qrow;
    float4* kn = (float4*)&Ks[r * QSTR];
#pragma unroll
    for (int i = 0; i < 4; ++i) kn[g * 4 + i] = s4[g * 4 + i];
    const float4* sr = (const float4*)(qrow + DNOPE);
    float4* qr = (float4*)&Qs[r * QSTR + DKVR];
    qr[g * 2 + 0] = sr[g * 2 + 0];
    qr[g * 2 + 1] = sr[g * 2 + 1];
  }
  __syncthreads();
  // ---- q_abs[r][k] = sum_d qnope[r][d] * Wup[h*256+d][k]; thread does k in [g*64, g*64+64)
  {
    float4 acc[16];
#pragma unroll
    for (int i = 0; i < 16; ++i) acc[i] = make_float4(0.f, 0.f, 0.f, 0.f);
    const float4* wb = (const float4*)(Wup + (size_t)(h * 256) * DKVR) + g * 16;
    const float* qn = &Ks[r * QSTR];
    for (int d = 0; d < DNOPE; ++d) {
      const float qv = qn[d];
      const float4* wr = wb + (size_t)d * (DKVR / 4);
#pragma unroll
      for (int i = 0; i < 16; ++i) {
        float4 w = wr[i];
        acc[i].x += qv * w.x; acc[i].y += qv * w.y; acc[i].z += qv * w.z; acc[i].w += qv * w.w;
      }
    }
    float4* qd = (float4*)&Qs[r * QSTR] + g * 16;
#pragma unroll
    for (int i = 0; i < 16; ++i) qd[i] = acc[i];
  }
  __syncthreads();

  const float scale = 0.07216878364870323f;  // 1/sqrt(192)
  float4 o4[16];
#pragma unroll
  for (int i = 0; i < 16; ++i) o4[i] = make_float4(0.f, 0.f, 0.f, 0.f);
  float mrow = -INFINITY, ssum = 0.f;
  const int rot = g * 2;
  const int ntiles = (l0 >> 5) + 1;

  for (int it = 0; it < ntiles; ++it) {
    const int t0 = it << 5;
    // stage K/V tile (576 floats per row; thread: row r, float4s [g*18, g*18+18))
    {
      const float4* src = (const float4*)(kvc + (size_t)(b * LQ + t0 + r) * DKC) + g * 18;
      float4* dst = (float4*)&Ks[r * QSTR] + g * 18;
#pragma unroll
      for (int i = 0; i < 18; ++i) dst[i] = src[i];
    }
    __syncthreads();
    // scores for columns t = t0 + g + 8*j
    float s0 = 0.f, s1 = 0.f, s2 = 0.f, s3 = 0.f;
    {
      const float4* qp = (const float4*)&Qs[r * QSTR];
      const float4* k0p = (const float4*)&Ks[(g + 0) * QSTR];
      const float4* k1p = (const float4*)&Ks[(g + 8) * QSTR];
      const float4* k2p = (const float4*)&Ks[(g + 16) * QSTR];
      const float4* k3p = (const float4*)&Ks[(g + 24) * QSTR];
#pragma unroll 4
      for (int k4 = 0; k4 < 144; ++k4) {
        const float4 qv = qp[k4];
        const float4 a = k0p[k4], bb = k1p[k4], c = k2p[k4], d = k3p[k4];
        s0 += qv.x * a.x + qv.y * a.y + qv.z * a.z + qv.w * a.w;
        s1 += qv.x * bb.x + qv.y * bb.y + qv.z * bb.z + qv.w * bb.w;
        s2 += qv.x * c.x + qv.y * c.y + qv.z * c.z + qv.w * c.w;
        s3 += qv.x * d.x + qv.y * d.y + qv.z * d.z + qv.w * d.w;
      }
    }
    const int l = l0 + r;
    s0 = (t0 + g + 0  <= l) ? s0 * scale : -INFINITY;
    s1 = (t0 + g + 8  <= l) ? s1 * scale : -INFINITY;
    s2 = (t0 + g + 16 <= l) ? s2 * scale : -INFINITY;
    s3 = (t0 + g + 24 <= l) ? s3 * scale : -INFINITY;
    float mt = fmaxf(fmaxf(s0, s1), fmaxf(s2, s3));
    mt = fmaxf(mt, __shfl_xor(mt, 1, 64));
    mt = fmaxf(mt, __shfl_xor(mt, 2, 64));
    mt = fmaxf(mt, __shfl_xor(mt, 4, 64));
    const float mnew = fmaxf(mrow, mt);
    const float corr = __expf(mrow - mnew);
    const float p0 = __expf(s0 - mnew);
    const float p1 = __expf(s1 - mnew);
    const float p2 = __expf(s2 - mnew);
    const float p3 = __expf(s3 - mnew);
    Ps[r * 32 + g + 0]  = p0;
    Ps[r * 32 + g + 8]  = p1;
    Ps[r * 32 + g + 16] = p2;
    Ps[r * 32 + g + 24] = p3;
    float psum = p0 + p1 + p2 + p3;
    psum += __shfl_xor(psum, 1, 64);
    psum += __shfl_xor(psum, 2, 64);
    psum += __shfl_xor(psum, 4, 64);
    ssum = ssum * corr + psum;
    mrow = mnew;
#pragma unroll
    for (int i = 0; i < 16; ++i) {
      o4[i].x *= corr; o4[i].y *= corr; o4[i].z *= corr; o4[i].w *= corr;
    }
    // O update: thread owns row r, col-quads g*16 + ((ii+rot)&15)
    {
      const float* pr = &Ps[r * 32];
      for (int t = 0; t < 32; ++t) {
        const float p = pr[t];
        const float4* vr = (const float4*)&Ks[t * QSTR] + g * 16;
#pragma unroll
        for (int ii = 0; ii < 16; ++ii) {
          const float4 v = vr[(ii + rot) & 15];
          o4[ii].x += p * v.x; o4[ii].y += p * v.y; o4[ii].z += p * v.z; o4[ii].w += p * v.w;
        }
      }
    }
    __syncthreads();
  }

  // ---- normalize and stage O into Ks[r][0:512]
  {
    const float inv = 1.f / ssum;
    float4* od = (float4*)&Ks[r * QSTR] + g * 16;
#pragma unroll
    for (int ii = 0; ii < 16; ++ii) {
      float4 v = o4[ii];
      od[(ii + rot) & 15] = make_float4(v.x * inv, v.y * inv, v.z * inv, v.w * inv);
    }
  }
  __syncthreads();
  // ---- v epilogue: vout[b, l0+r, h*128 + d] = sum_k O[r][k] * Wup[h*256+128+d][k]
  {
    const float4* orow = (const float4*)&Ks[r * QSTR];
    float* vo = vout + (size_t)(b * LQ + l0 + r) * (NHEAD * DV) + h * DV;
    for (int dd = 0; dd < 16; ++dd) {
      const int d = g * 16 + dd;
      const float4* wr = (const float4*)(Wup + (size_t)(h * 256 + DNOPE + d) * DKVR);
      float ax = 0.f, ay = 0.f, az = 0.f, aw = 0.f;
#pragma unroll 4
      for (int k4 = 0; k4 < 128; ++k4) {
        const float4 ov = orow[k4];
        const float4 w = wr[k4];
        ax += ov.x * w.x; ay += ov.y * w.y; az += ov.z * w.z; aw += ov.w * w.w;
      }
      vo[d] = ax + ay + az + aw;
    }
  }
}

extern "C" void kernel_launch(void* const* d_in, const int* in_sizes, int n_in,
                              void* d_out, int out_size, void* d_ws, size_t ws_size,
                              hipStream_t stream) {
  const float* x        = (const float*)d_in[0];
  // d_in[1] = start_pos (0), d_in[3] = mask (== causal) — both folded in.
  const float* freq     = (const float*)d_in[2];
  const float* Wq_down  = (const float*)d_in[4];
  const float* Wq_up    = (const float*)d_in[5];
  const float* Wkv_down = (const float*)d_in[6];
  const float* Wkv_up   = (const float*)d_in[7];
  const float* Wout     = (const float*)d_in[8];
  const float* rms_q_w  = (const float*)d_in[9];
  const float* rms_kv_w = (const float*)d_in[10];
  float* out = (float*)d_out;

  float* ws   = (float*)d_ws;
  float* t0   = ws;                              // 4096*1024
  float* q    = t0 + (size_t)4096 * 1024;        // 4096*3072
  float* kv   = q + (size_t)4096 * 3072;         // 4096*576
  float* kvc  = kv + (size_t)4096 * 576;         // 4096*576
  float* vout = kvc + (size_t)4096 * 576;        // 4096*2048

  const dim3 blk(256);
  // q_lat_pre = x @ Wq_down^T   (4096,2048)x(1024,2048) -> (4096,1024)
  gemm_nt<<<dim3(1024 / 64, 4096 / 64), blk, 0, stream>>>(x, Wq_down, t0, 2048, 2048, 2048, 1024);
  // rmsnorm in place
  rmsnorm1024<<<4096, 64, 0, stream>>>(t0, rms_q_w);
  // q = q_lat @ Wq_up^T -> (4096,3072)
  gemm_nt<<<dim3(3072 / 64, 4096 / 64), blk, 0, stream>>>(t0, Wq_up, q, 1024, 1024, 1024, 3072);
  // kv = x @ Wkv_down^T -> (4096,576)
  gemm_nt<<<dim3(576 / 64, 4096 / 64), blk, 0, stream>>>(x, Wkv_down, kv, 2048, 2048, 2048, 576);
  // kvc: rmsnorm(512) + rope(64)
  prep_kv<<<4096, 64, 0, stream>>>(kv, freq, rms_kv_w, kvc);
  // rope q in place
  rope_q<<<4096, 64, 0, stream>>>(q, freq);
  // fused attention -> vout (4096, 2048)
  mla_attn<<<dim3(LQ / 32, NHEAD, 4), blk, 0, stream>>>(q, kvc, Wkv_up, vout);
  // out = vout @ Wout^T -> (4096, 2048)
  gemm_nt<<<dim3(2048 / 64, 4096 / 64), blk, 0, stream>>>(vout, Wout, out, 2048, 2048, 2048, 2048);
}

// Round 3
// 819.449 us; speedup vs baseline: 11.0740x; 11.0740x over previous
//
#include <hip/hip_runtime.h>
#include <stdint.h>

typedef float f32x4 __attribute__((ext_vector_type(4)));
typedef short bf16x8 __attribute__((ext_vector_type(8)));
typedef int i32x4 __attribute__((ext_vector_type(4)));
typedef unsigned short u16;
typedef unsigned int u32;

#define MFMA16(a, b, c) __builtin_amdgcn_mfma_f32_16x16x32_bf16(a, b, c, 0, 0, 0)

__device__ __forceinline__ u16 f2b(float f) {
  union { float f; u32 u; } a; a.f = f;
  u32 r = a.u + 0x7FFF + ((a.u >> 16) & 1);
  return (u16)(r >> 16);
}
__device__ __forceinline__ float b2f(u16 b) {
  union { u32 u; float f; } a; a.u = ((u32)b) << 16;
  return a.f;
}
__device__ __forceinline__ u32 pk2(float x, float y) {
  return (u32)f2b(x) | ((u32)f2b(y) << 16);
}

// quad-gather: lanes (m, g) each hold lo (4 vals at idx 4g+j) and hi (idx 16+4g+j),
// packed as 2 dwords each. Returns 8 vals at idx 8g..8g+7 for this lane.
// Select happens AFTER the shfl (target's need, not source's guess).
__device__ __forceinline__ bf16x8 quad_gather(int g, int m, u32 lo0, u32 lo1, u32 hi0, u32 hi1) {
  const int srcA = m + 16 * ((2 * g) & 3);
  const int srcB = m + 16 * ((2 * g + 1) & 3);
  const u32 Al0 = __shfl((int)lo0, srcA, 64), Al1 = __shfl((int)lo1, srcA, 64);
  const u32 Ah0 = __shfl((int)hi0, srcA, 64), Ah1 = __shfl((int)hi1, srcA, 64);
  const u32 Bl0 = __shfl((int)lo0, srcB, 64), Bl1 = __shfl((int)lo1, srcB, 64);
  const u32 Bh0 = __shfl((int)hi0, srcB, 64), Bh1 = __shfl((int)hi1, srcB, 64);
  i32x4 r;
  r.x = (int)((g < 2) ? Al0 : Ah0);
  r.y = (int)((g < 2) ? Al1 : Ah1);
  r.z = (int)((g < 2) ? Bl0 : Bh0);
  r.w = (int)((g < 2) ? Bl1 : Bh1);
  return __builtin_bit_cast(bf16x8, r);
}

// ---------------- fp32 -> bf16 convert (grid*256*8 elems exactly) ----------------
__global__ __launch_bounds__(256) void conv_f2b(const float* __restrict__ s, u16* __restrict__ d) {
  const size_t idx = (size_t)blockIdx.x * 256 + threadIdx.x;
  const float4* s4 = (const float4*)s;
  float4 a = s4[idx * 2], b = s4[idx * 2 + 1];
  i32x4 o;
  o.x = (int)pk2(a.x, a.y); o.y = (int)pk2(a.z, a.w);
  o.z = (int)pk2(b.x, b.y); o.w = (int)pk2(b.z, b.w);
  *(i32x4*)(d + idx * 8) = o;
}

// ---------------- Wkv_down (576,2048) fp32 -> (640,2048) bf16, zero-pad rows ----------------
__global__ __launch_bounds__(256) void conv_pad_kvd(const float* __restrict__ s, u16* __restrict__ d) {
  const size_t idx = (size_t)blockIdx.x * 256 + threadIdx.x;
  const size_t e0 = idx * 8;
  const int row = (int)(e0 >> 11);
  i32x4 o;
  if (row < 576) {
    const float4* s4 = (const float4*)s;
    float4 a = s4[idx * 2], b = s4[idx * 2 + 1];
    o.x = (int)pk2(a.x, a.y); o.y = (int)pk2(a.z, a.w);
    o.z = (int)pk2(b.x, b.y); o.w = (int)pk2(b.z, b.w);
  } else {
    o.x = 0; o.y = 0; o.z = 0; o.w = 0;
  }
  *(i32x4*)(d + e0) = o;
}

// ---------------- wupt[h][k][d] (bf16) = Wkv_up[h*256+d][k], d in [0,128) ----------------
__global__ __launch_bounds__(256) void transpose_wup(const float* __restrict__ s, u16* __restrict__ d) {
  __shared__ float tile[32][33];
  const int tx = threadIdx.x & 31, ty = threadIdx.x >> 5;
  const int h = blockIdx.z, nt = blockIdx.x, dt = blockIdx.y;
#pragma unroll
  for (int i = 0; i < 4; ++i)
    tile[ty + i * 8][tx] = s[(size_t)(h * 256 + dt * 32 + ty + i * 8) * 512 + nt * 32 + tx];
  __syncthreads();
#pragma unroll
  for (int i = 0; i < 4; ++i)
    d[(size_t)(h * 512 + nt * 32 + ty + i * 8) * 128 + dt * 32 + tx] = f2b(tile[tx][ty + i * 8]);
}

// ---------------- kvT[b][c][t] (bf16) = kvc[b*1024+t][c], c in [0,512) ----------------
__global__ __launch_bounds__(256) void transpose_kvT(const u16* __restrict__ s, u16* __restrict__ d) {
  __shared__ u16 tile[32][33];
  const int tx = threadIdx.x & 31, ty = threadIdx.x >> 5;
  const int b = blockIdx.z, tt = blockIdx.x, ct = blockIdx.y;
#pragma unroll
  for (int i = 0; i < 4; ++i)
    tile[ty + i * 8][tx] = s[(size_t)(b * 1024 + tt * 32 + ty + i * 8) * 576 + ct * 32 + tx];
  __syncthreads();
#pragma unroll
  for (int i = 0; i < 4; ++i)
    d[(size_t)(b * 512 + ct * 32 + ty + i * 8) * 1024 + tt * 32 + tx] = tile[tx][ty + i * 8];
}

// ---------------- RMSNorm rows of 1024: f32 in -> bf16 out ----------------
__global__ __launch_bounds__(64) void rmsnorm1024_b(const float* __restrict__ t, const float* __restrict__ w,
                                                    u16* __restrict__ o) {
  const int row = blockIdx.x, lane = threadIdx.x;
  const float4* p = (const float4*)(t + (size_t)row * 1024);
  const float4* w4 = (const float4*)w;
  float4 v[4];
  float ss = 0.f;
#pragma unroll
  for (int i = 0; i < 4; ++i) {
    v[i] = p[lane * 4 + i];
    ss += v[i].x * v[i].x + v[i].y * v[i].y + v[i].z * v[i].z + v[i].w * v[i].w;
  }
#pragma unroll
  for (int off = 32; off >= 1; off >>= 1) ss += __shfl_xor(ss, off, 64);
  const float rms = rsqrtf(ss * (1.0f / 1024.0f) + 1e-6f);
  u16* ob = o + (size_t)row * 1024 + lane * 16;
#pragma unroll
  for (int i2 = 0; i2 < 2; ++i2) {
    float4 a = v[i2 * 2], wa = w4[lane * 4 + i2 * 2];
    float4 b = v[i2 * 2 + 1], wb = w4[lane * 4 + i2 * 2 + 1];
    i32x4 pk;
    pk.x = (int)pk2(a.x * rms * wa.x, a.y * rms * wa.y);
    pk.y = (int)pk2(a.z * rms * wa.z, a.w * rms * wa.w);
    pk.z = (int)pk2(b.x * rms * wb.x, b.y * rms * wb.y);
    pk.w = (int)pk2(b.z * rms * wb.z, b.w * rms * wb.w);
    *(i32x4*)(ob + i2 * 8) = pk;
  }
}

// ---------------- kvp (4096,640 f32) -> kvc (4096,576 bf16): rmsnorm 512 + rope 64 ----------------
__global__ __launch_bounds__(64) void prep_kv(const float* __restrict__ kv, const float* __restrict__ freq,
                                              const float* __restrict__ w, u16* __restrict__ kvc) {
  const int row = blockIdx.x, lane = threadIdx.x;
  const int l = row & 1023;
  const float* src = kv + (size_t)row * 640;
  const float4* s4 = (const float4*)src;
  const float4* w4 = (const float4*)w;
  float4 v[2];
  float ss = 0.f;
#pragma unroll
  for (int i = 0; i < 2; ++i) {
    v[i] = s4[lane * 2 + i];
    ss += v[i].x * v[i].x + v[i].y * v[i].y + v[i].z * v[i].z + v[i].w * v[i].w;
  }
#pragma unroll
  for (int off = 32; off >= 1; off >>= 1) ss += __shfl_xor(ss, off, 64);
  const float rms = rsqrtf(ss * (1.0f / 512.0f) + 1e-6f);
  u16* dst = kvc + (size_t)row * 576;
  {
    float4 a = v[0], wa = w4[lane * 2];
    float4 b = v[1], wb = w4[lane * 2 + 1];
    i32x4 pk;
    pk.x = (int)pk2(a.x * rms * wa.x, a.y * rms * wa.y);
    pk.y = (int)pk2(a.z * rms * wa.z, a.w * rms * wa.w);
    pk.z = (int)pk2(b.x * rms * wb.x, b.y * rms * wb.y);
    pk.w = (int)pk2(b.z * rms * wb.z, b.w * rms * wb.w);
    *(i32x4*)(dst + lane * 8) = pk;
  }
  if (lane < 32) {
    const int j = lane;
    const float re = src[512 + 2 * j], im = src[512 + 2 * j + 1];
    const float c = freq[(l * 32 + j) * 2], s = freq[(l * 32 + j) * 2 + 1];
    dst[512 + 2 * j] = f2b(re * c - im * s);
    dst[512 + 2 * j + 1] = f2b(re * s + im * c);
  }
}

// ---------------- bf16 NT GEMM: C[m,n] = sum_k A[m,k]*B[n,k]; 128x128 tile, BK=64 ----------------
// Reg-staged LDS (stride 72 = bank-clean), no global_load_lds this round.
template <typename OUT>
__global__ __launch_bounds__(256) void gemm_nt_bf16(const u16* __restrict__ A, const u16* __restrict__ B,
                                                    OUT* __restrict__ C, int K, int lda, int ldb, int ldc) {
  __shared__ u16 lA[128 * 72];
  __shared__ u16 lB[128 * 72];
  const int tid = threadIdx.x, lane = tid & 63, w = tid >> 6;
  const int m = lane & 15, g = lane >> 4;
  const int wm = (w & 1) * 64, wn = (w >> 1) * 64;
  const int m0 = blockIdx.y * 128, n0 = blockIdx.x * 128;
  f32x4 acc[4][4];
#pragma unroll
  for (int i = 0; i < 4; ++i)
#pragma unroll
    for (int j = 0; j < 4; ++j) acc[i][j] = (f32x4)(0.0f);

  for (int k0 = 0; k0 < K; k0 += 64) {
    __syncthreads();
#pragma unroll
    for (int k = 0; k < 4; ++k) {
      const int s = tid + k * 256;          // 0..1023
      const int row = s >> 3, c8 = (s & 7) * 8;
      *(bf16x8*)&lA[row * 72 + c8] = *(const bf16x8*)(A + (size_t)(m0 + row) * lda + k0 + c8);
      *(bf16x8*)&lB[row * 72 + c8] = *(const bf16x8*)(B + (size_t)(n0 + row) * ldb + k0 + c8);
    }
    __syncthreads();
#pragma unroll
    for (int ks = 0; ks < 2; ++ks) {
      bf16x8 af[4], bfr[4];
#pragma unroll
      for (int i = 0; i < 4; ++i) {
        af[i] = *(const bf16x8*)&lA[(wm + i * 16 + m) * 72 + ks * 32 + g * 8];
        bfr[i] = *(const bf16x8*)&lB[(wn + i * 16 + m) * 72 + ks * 32 + g * 8];
      }
#pragma unroll
      for (int i = 0; i < 4; ++i)
#pragma unroll
        for (int j = 0; j < 4; ++j) acc[i][j] = MFMA16(af[i], bfr[j], acc[i][j]);
    }
  }
  // C/D layout: col = lane&15, row = (lane>>4)*4 + reg  [m89/m91 verified]
#pragma unroll
  for (int i = 0; i < 4; ++i)
#pragma unroll
    for (int j = 0; j < 4; ++j)
#pragma unroll
      for (int jj = 0; jj < 4; ++jj) {
        const size_t off = (size_t)(m0 + wm + i * 16 + g * 4 + jj) * ldc + n0 + wn + j * 16 + m;
        if constexpr (sizeof(OUT) == 2) C[off] = f2b(acc[i][j][jj]);
        else C[off] = acc[i][j][jj];
      }
}

// ---------------- fused MLA attention: q_abs + rope(q) + flash + Wv epilogue ----------------
// grid (16 qtiles, 16 heads, 4 batch), 256 thr (4 waves x 16 q-rows).
__global__ __launch_bounds__(256, 2) void mla_attn(
    const u16* __restrict__ q_bf,   // (4096, 3072) raw q (un-roped)
    const u16* __restrict__ wupt,   // (16, 512, 128) = Wup_nope^T per head
    const u16* __restrict__ kvc,    // (4096, 576)
    const u16* __restrict__ kvT,    // (4, 512, 1024) latent transposed
    const float* __restrict__ freq, // (1024, 32, 2)
    const u16* __restrict__ wkvu,   // (4096, 512) full Wkv_up bf16
    u16* __restrict__ vout) {       // (4096, 2048)
  __shared__ u16 KL[32 * 600];   // K tile row-major, padded stride 600
  __shared__ u16 VT[512 * 40];   // V^T tile, padded stride 40
  const int tid = threadIdx.x, lane = tid & 63, w = tid >> 6;
  const int m = lane & 15, g = lane >> 4;
  const int b = blockIdx.z, h = blockIdx.y, l0 = blockIdx.x * 64;
  const int row = l0 + w * 16 + m;          // q row within batch = position l
  const float scale = 0.07216878364870323f; // 1/sqrt(192)

  // ---- prologue: qh[0..15] = q_abs fragments (B-operand: n=qrow=m, k consec 8)
  bf16x8 qh[18];
  const u16* qrow = q_bf + ((size_t)b * 1024 + row) * 3072 + h * 192;
  {
    bf16x8 qn[4];
#pragma unroll
    for (int dk = 0; dk < 4; ++dk) qn[dk] = *(const bf16x8*)(qrow + dk * 32 + g * 8);
    const u16* wu = wupt + (size_t)h * 512 * 128;
#pragma unroll
    for (int ks = 0; ks < 16; ++ks) {
      f32x4 a0 = (f32x4)(0.0f), a1 = (f32x4)(0.0f);
#pragma unroll
      for (int dk = 0; dk < 4; ++dk) {
        bf16x8 w0 = *(const bf16x8*)(wu + (size_t)((2 * ks) * 16 + m) * 128 + dk * 32 + g * 8);
        bf16x8 w1 = *(const bf16x8*)(wu + (size_t)((2 * ks + 1) * 16 + m) * 128 + dk * 32 + g * 8);
        a0 = MFMA16(w0, qn[dk], a0);   // D: col=qrow(m), row=kcol-local 4g+reg
        a1 = MFMA16(w1, qn[dk], a1);
      }
      qh[ks] = quad_gather(g, m, pk2(a0[0], a0[1]), pk2(a0[2], a0[3]),
                                 pk2(a1[0], a1[1]), pk2(a1[2], a1[3]));
    }
    // rope frags qh[16],qh[17]: k = 512 + t*32 + g*8 + j
#pragma unroll
    for (int t = 0; t < 2; ++t) {
      bf16x8 qr = *(const bf16x8*)(qrow + 128 + t * 32 + g * 8);
      u32 dw[4];
#pragma unroll
      for (int pp = 0; pp < 4; ++pp) {
        const int pi = t * 16 + g * 4 + pp;
        const float c = freq[(row * 32 + pi) * 2], s = freq[(row * 32 + pi) * 2 + 1];
        const float re = b2f((u16)qr[2 * pp]), im = b2f((u16)qr[2 * pp + 1]);
        dw[pp] = pk2(re * c - im * s, re * s + im * c);
      }
      i32x4 r; r.x = (int)dw[0]; r.y = (int)dw[1]; r.z = (int)dw[2]; r.w = (int)dw[3];
      qh[16 + t] = __builtin_bit_cast(bf16x8, r);
    }
  }

  f32x4 o[32];
#pragma unroll
  for (int i = 0; i < 32; ++i) o[i] = (f32x4)(0.0f);
  float mrow = -INFINITY, ssum = 0.f;
  const int nt = (l0 >> 5) + 2;
  const u16* kvb = kvc + (size_t)b * 1024 * 576;
  const u16* kvTb = kvT + (size_t)b * 512 * 1024;

  for (int it = 0; it < nt; ++it) {
    const int t0 = it * 32;
    __syncthreads();
    {  // stage K tile [32][600] from kvc (9 vec8/thread)
      const u16* kb = kvb + (size_t)t0 * 576;
#pragma unroll
      for (int k = 0; k < 9; ++k) {
        const int s = tid + k * 256;        // 0..2303
        const int t = s / 72, c8 = (s % 72) * 8;
        *(bf16x8*)&KL[t * 600 + c8] = *(const bf16x8*)(kb + (size_t)t * 576 + c8);
      }
      // stage V^T tile [512][40] from kvT (8 vec8/thread)
#pragma unroll
      for (int k = 0; k < 8; ++k) {
        const int s = tid + k * 256;        // 0..2047
        const int c = s >> 2, tq = (s & 3) * 8;
        *(bf16x8*)&VT[c * 40 + tq] = *(const bf16x8*)(kvTb + (size_t)c * 1024 + t0 + tq);
      }
    }
    __syncthreads();
    const bool act = t0 <= l0 + w * 16 + 15;   // wave-uniform
    if (act) {
      // QK^T (swapped): A = K rows (t-local = lane&15 per half), B = qh
      f32x4 st0 = (f32x4)(0.0f), st1 = (f32x4)(0.0f);
#pragma unroll
      for (int ks = 0; ks < 18; ++ks) {
        bf16x8 a0 = *(const bf16x8*)&KL[m * 600 + ks * 32 + g * 8];
        bf16x8 a1 = *(const bf16x8*)&KL[(m + 16) * 600 + ks * 32 + g * 8];
        st0 = MFMA16(a0, qh[ks], st0);
        st1 = MFMA16(a1, qh[ks], st1);
      }
      // softmax: lane holds S[t0 + 4g+j (+16)][qrow m]
      float p[8];
      float mt = -INFINITY;
#pragma unroll
      for (int j = 0; j < 4; ++j) {
        const int ta = t0 + 4 * g + j, tb = ta + 16;
        const float sa = (ta <= row) ? st0[j] * scale : -INFINITY;
        const float sb = (tb <= row) ? st1[j] * scale : -INFINITY;
        p[j] = sa; p[4 + j] = sb;
        mt = fmaxf(mt, fmaxf(sa, sb));
      }
      mt = fmaxf(mt, __shfl_xor(mt, 16, 64));
      mt = fmaxf(mt, __shfl_xor(mt, 32, 64));
      const float mnew = fmaxf(mrow, mt);
      const float corr = __expf(mrow - mnew);
      float psum = 0.f;
#pragma unroll
      for (int i = 0; i < 8; ++i) { p[i] = __expf(p[i] - mnew); psum += p[i]; }
      psum += __shfl_xor(psum, 16, 64);
      psum += __shfl_xor(psum, 32, 64);
      ssum = ssum * corr + psum;
      mrow = mnew;
      // P redistribution: lane gets P[qrow m][t' = 8g..8g+7] as bf16x8 A-operand
      const bf16x8 pa = quad_gather(g, m, pk2(p[0], p[1]), pk2(p[2], p[3]),
                                          pk2(p[4], p[5]), pk2(p[6], p[7]));
      // rescale O (O rows are 4g+j)
      float cj[4];
#pragma unroll
      for (int j = 0; j < 4; ++j) cj[j] = __shfl(corr, 4 * g + j, 64);
#pragma unroll
      for (int i = 0; i < 32; ++i) {
        o[i][0] *= cj[0]; o[i][1] *= cj[1]; o[i][2] *= cj[2]; o[i][3] *= cj[3];
      }
      // PV: B[k=t'][n=vd] from VT[(nf*16+m)*40 + g*8]
#pragma unroll
      for (int nf = 0; nf < 32; ++nf) {
        const bf16x8 bfr = *(const bf16x8*)&VT[(nf * 16 + m) * 40 + g * 8];
        o[nf] = MFMA16(pa, bfr, o[nf]);
      }
    }
  }

  // normalize
  {
    const float inv = 1.f / ssum;
    float ij[4];
#pragma unroll
    for (int j = 0; j < 4; ++j) ij[j] = __shfl(inv, 4 * g + j, 64);
#pragma unroll
    for (int i = 0; i < 32; ++i) {
      o[i][0] *= ij[0]; o[i][1] *= ij[1]; o[i][2] *= ij[2]; o[i][3] *= ij[3];
    }
  }
  __syncthreads();   // all waves done with KL/VT; reuse KL as O staging
  // Wv epilogue: vo[qrow][d] = sum_k O[qrow][k] * Wv[d][k]
  u16* Ob = &KL[w * 4224];                 // per-wave 16 x 264
  const u16* wv = wkvu + (size_t)(h * 256 + 128) * 512;
  f32x4 vo[8];
#pragma unroll
  for (int i = 0; i < 8; ++i) vo[i] = (f32x4)(0.0f);
#pragma unroll
  for (int hh = 0; hh < 2; ++hh) {
#pragma unroll
    for (int i = 0; i < 16; ++i)
#pragma unroll
      for (int j = 0; j < 4; ++j)
        Ob[(4 * g + j) * 264 + i * 16 + m] = f2b(o[hh * 16 + i][j]);
    __syncthreads();
#pragma unroll
    for (int ks = 0; ks < 8; ++ks) {
      const bf16x8 oa = *(const bf16x8*)&Ob[m * 264 + ks * 32 + g * 8];
#pragma unroll
      for (int df = 0; df < 8; ++df) {
        const bf16x8 wb = *(const bf16x8*)(wv + (size_t)(df * 16 + m) * 512 + hh * 256 + ks * 32 + g * 8);
        vo[df] = MFMA16(oa, wb, vo[df]);
      }
    }
    __syncthreads();
  }
  {
    u16* vp = vout + ((size_t)(b * 1024 + l0 + w * 16)) * 2048 + h * 128;
#pragma unroll
    for (int df = 0; df < 8; ++df)
#pragma unroll
      for (int j = 0; j < 4; ++j)
        vp[(size_t)(4 * g + j) * 2048 + df * 16 + m] = f2b(vo[df][j]);
  }
}

extern "C" void kernel_launch(void* const* d_in, const int* in_sizes, int n_in,
                              void* d_out, int out_size, void* d_ws, size_t ws_size,
                              hipStream_t stream) {
  const float* x        = (const float*)d_in[0];
  const float* freq     = (const float*)d_in[2];
  const float* Wq_down  = (const float*)d_in[4];
  const float* Wq_up    = (const float*)d_in[5];
  const float* Wkv_down = (const float*)d_in[6];
  const float* Wkv_up   = (const float*)d_in[7];
  const float* Wout     = (const float*)d_in[8];
  const float* rms_q_w  = (const float*)d_in[9];
  const float* rms_kv_w = (const float*)d_in[10];
  float* out = (float*)d_out;

  // workspace layout — total ~104 MB (< Round-0's proven 120.6 MB)
  char* p = (char*)d_ws;
  auto alloc = [&](size_t bytes) { char* r = p; p += (bytes + 255) & ~(size_t)255; return r; };
  u16* wqd    = (u16*)alloc((size_t)1024 * 2048 * 2);
  u16* wqu    = (u16*)alloc((size_t)3072 * 1024 * 2);
  u16* wkvd   = (u16*)alloc((size_t)640 * 2048 * 2);
  u16* wkvu   = (u16*)alloc((size_t)4096 * 512 * 2);
  u16* wupt   = (u16*)alloc((size_t)16 * 512 * 128 * 2);
  u16* woutb  = (u16*)alloc((size_t)2048 * 2048 * 2);
  u16* x_bf   = (u16*)alloc((size_t)4096 * 2048 * 2);
  u16* q_bf   = (u16*)alloc((size_t)4096 * 3072 * 2);
  u16* t0b    = (u16*)alloc((size_t)4096 * 1024 * 2);
  u16* kvc    = (u16*)alloc((size_t)4096 * 576 * 2);
  u16* kvT    = (u16*)alloc((size_t)4 * 512 * 1024 * 2);
  char* R     = alloc((size_t)4096 * 1024 * 4);   // t0 f32 | kvp f32 | vout bf16 (time-disjoint)
  float* t0   = (float*)R;
  float* kvp  = (float*)R;
  u16*   vout = (u16*)R;

  // dtype conversions / weight transposes
  conv_f2b<<<4096, 256, 0, stream>>>(x, x_bf);
  conv_f2b<<<1024, 256, 0, stream>>>(Wq_down, wqd);
  conv_f2b<<<1536, 256, 0, stream>>>(Wq_up, wqu);
  conv_f2b<<<1024, 256, 0, stream>>>(Wkv_up, wkvu);
  conv_f2b<<<2048, 256, 0, stream>>>(Wout, woutb);
  conv_pad_kvd<<<640, 256, 0, stream>>>(Wkv_down, wkvd);
  transpose_wup<<<dim3(16, 4, 16), 256, 0, stream>>>(Wkv_up, wupt);
  // q path
  gemm_nt_bf16<float><<<dim3(8, 32), 256, 0, stream>>>(x_bf, wqd, t0, 2048, 2048, 2048, 1024);
  rmsnorm1024_b<<<4096, 64, 0, stream>>>(t0, rms_q_w, t0b);
  gemm_nt_bf16<u16><<<dim3(24, 32), 256, 0, stream>>>(t0b, wqu, q_bf, 1024, 1024, 1024, 3072);
  // kv path (t0 region dead -> kvp)
  gemm_nt_bf16<float><<<dim3(5, 32), 256, 0, stream>>>(x_bf, wkvd, kvp, 2048, 2048, 2048, 640);
  prep_kv<<<4096, 64, 0, stream>>>(kvp, freq, rms_kv_w, kvc);
  transpose_kvT<<<dim3(32, 16, 4), 256, 0, stream>>>(kvc, kvT);
  // fused attention (kvp dead -> vout)
  mla_attn<<<dim3(16, 16, 4), 256, 0, stream>>>(q_bf, wupt, kvc, kvT, freq, wkvu, vout);
  // final projection
  gemm_nt_bf16<float><<<dim3(16, 32), 256, 0, stream>>>(vout, woutb, out, 2048, 2048, 2048, 2048);
}